// Round 13
// baseline (137.655 us; speedup 1.0000x reference)
//
#include <hip/hip_runtime.h>

#define DEV __device__ __forceinline__

typedef __bf16 bf16x8 __attribute__((ext_vector_type(8)));
typedef float f32x4 __attribute__((ext_vector_type(4)));
typedef float f32x16 __attribute__((ext_vector_type(16)));
typedef unsigned u32x4 __attribute__((ext_vector_type(4)));

constexpr int S_LEN = 2048;
constexpr int DMODEL = 1024;
constexpr int NHEAD = 16;
constexpr int HDIM = 64;
constexpr int BATCH = 2;
constexpr int MROWS = BATCH * S_LEN;  // 4096
constexpr float QSCALE = 0.125f * 1.44269504088896f;  // 1/sqrt(64) * log2(e)

DEV short f2bf(float x) {
  unsigned u = __builtin_bit_cast(unsigned, x);
  unsigned r = u + 0x7fffu + ((u >> 16) & 1u);
  return (short)(r >> 16);
}

#define MFMA16(a, b, c) __builtin_amdgcn_mfma_f32_16x16x32_bf16((a), (b), (c), 0, 0, 0)
#define MFMA32(a, b, c) __builtin_amdgcn_mfma_f32_32x32x16_bf16((a), (b), (c), 0, 0, 0)
#define GLL16(g, l)                                                                     \
  __builtin_amdgcn_global_load_lds((const __attribute__((address_space(1))) void*)(g),  \
                                   (__attribute__((address_space(3))) void*)(l), 16, 0, 0)

DEV unsigned cvt_pk_bf16(float a, float b) {
  unsigned r;
  asm("v_cvt_pk_bf16_f32 %0, %1, %2" : "=v"(r) : "v"(a), "v"(b));
  return r;
}
DEV void swap32(unsigned& a, unsigned& b) {
  asm("v_permlane32_swap_b32 %0, %1" : "+v"(a), "+v"(b));
}

// ---------------- fp32 -> bf16 converts ----------------
__global__ void cvt_kernel(const float* __restrict__ in, short* __restrict__ out, int n) {
  int i = (blockIdx.x * blockDim.x + threadIdx.x) * 4;
  const int stride = gridDim.x * blockDim.x * 4;
  for (; i < n; i += stride) {
    float4 v = *(const float4*)&in[i];
    short4 r;
    r.x = f2bf(v.x);
    r.y = f2bf(v.y);
    r.z = f2bf(v.z);
    r.w = f2bf(v.w);
    *(short4*)&out[i] = r;
  }
}

__global__ void cvt_w4(const float* __restrict__ Wq, const float* __restrict__ Wk,
                       const float* __restrict__ Wv, const float* __restrict__ Wo,
                       short* __restrict__ out) {
  const float* src = blockIdx.y == 0 ? Wq : blockIdx.y == 1 ? Wk : blockIdx.y == 2 ? Wv : Wo;
  short* dst = out + (size_t)blockIdx.y * (DMODEL * DMODEL);
  int i = (blockIdx.x * blockDim.x + threadIdx.x) * 4;
  const int stride = gridDim.x * blockDim.x * 4;
  for (; i < DMODEL * DMODEL; i += stride) {
    float4 v = *(const float4*)&src[i];
    short4 r;
    r.x = f2bf(v.x);
    r.y = f2bf(v.y);
    r.z = f2bf(v.z);
    r.w = f2bf(v.w);
    *(short4*)&dst[i] = r;
  }
}

// ---------------- bf16 GEMM: C[m,e] = sum_k A[m,k] * Bt[e,k] ----------------
// 128x128 tile, BK=32 double-buffered (32KB LDS), counted vmcnt(4) + RAW barriers
// (loads stay in flight across the whole compute phase — T4; never drain in loop).
// XOR swizzle: LDS[row][sl] = global[row][sl ^ ((row>>1)&3)] (2-way max = free).
// mode 3: out epilogue (fp32 [M,N] + bias)
// mode 4: fused QKV epilogue; V third (tn>=16) computes SWAPPED mfma(Wv,x) so the
//         output is C^T at [e][m] and the V^T store is 32B-contiguous (no 2B scatter).
__global__ __launch_bounds__(256) void gemm_bt(const short* __restrict__ A,
                                               const short* __restrict__ Bt,
                                               short* __restrict__ outb,
                                               float* __restrict__ outf,
                                               const float* __restrict__ bias,
                                               const int mode) {
  constexpr int K = DMODEL;
  constexpr int N = DMODEL;
  constexpr int KT_N = K / 32;  // 32
  constexpr size_t XN = (size_t)MROWS * DMODEL;
  __shared__ short As[2][128 * 32];  // 8KB x2
  __shared__ short Bs[2][128 * 32];
  const int tid = threadIdx.x;
  const int w = tid >> 6, l = tid & 63;
  const int lr = l & 15, lh = l >> 4;
  const int wr = w >> 1, wc = w & 1;
  const int tm = blockIdx.x, tn = blockIdx.y;
  const bool vswap = (mode == 4) && (tn >= 16);  // V third: swapped operands

  f32x4 acc[4][4] = {};

#define GSTAGE(KT, BUF)                                                      \
  {                                                                          \
    _Pragma("unroll") for (int r = 0; r < 2; ++r) {                          \
      const int c = r * 256 + tid; /* chunk 0..511 */                        \
      const int row = c >> 2;                                                \
      const int g = (c & 3) ^ ((row >> 1) & 3); /* pre-swizzled source */    \
      GLL16(A + (size_t)(tm * 128 + row) * K + (KT)*32 + g * 8,              \
            &As[BUF][(r * 256 + w * 64) * 8]);                               \
      GLL16(Bt + (size_t)(tn * 128 + row) * K + (KT)*32 + g * 8,             \
            &Bs[BUF][(r * 256 + w * 64) * 8]);                               \
    }                                                                        \
  }

  GSTAGE(0, 0);

  for (int kt = 0; kt < KT_N; ++kt) {
    const int buf = kt & 1;
    if (kt + 1 < KT_N) {
      GSTAGE(kt + 1, buf ^ 1);  // issue next tile early; stays in flight
      asm volatile("s_waitcnt vmcnt(4)" ::: "memory");  // current tile landed
    } else {
      asm volatile("s_waitcnt vmcnt(0)" ::: "memory");
    }
    __builtin_amdgcn_s_barrier();  // raw: no compiler auto-drain

    bf16x8 af[4], bfr[4];
#pragma unroll
    for (int mi = 0; mi < 4; ++mi) {
      const int row = wr * 64 + mi * 16 + lr;
      af[mi] = *(const bf16x8*)&As[buf][row * 32 + 8 * (lh ^ ((row >> 1) & 3))];
    }
#pragma unroll
    for (int ni = 0; ni < 4; ++ni) {
      const int row = wc * 64 + ni * 16 + lr;
      bfr[ni] = *(const bf16x8*)&Bs[buf][row * 32 + 8 * (lh ^ ((row >> 1) & 3))];
    }
    if (vswap) {
#pragma unroll
      for (int mi = 0; mi < 4; ++mi)
#pragma unroll
        for (int ni = 0; ni < 4; ++ni)
          acc[mi][ni] = MFMA16(bfr[ni], af[mi], acc[mi][ni]);
    } else {
#pragma unroll
      for (int mi = 0; mi < 4; ++mi)
#pragma unroll
        for (int ni = 0; ni < 4; ++ni)
          acc[mi][ni] = MFMA16(af[mi], bfr[ni], acc[mi][ni]);
    }

    __builtin_amdgcn_s_barrier();  // reads of buf done before t+1 stages into it
  }
#undef GSTAGE

  // C/D frag layout: row = (l>>4)*4 + i, col = l&15
  const int m0 = tm * 128 + wr * 64;
  const int n0 = tn * 128 + wc * 64;
  if (mode == 3) {
#pragma unroll
    for (int mi = 0; mi < 4; ++mi)
#pragma unroll
      for (int ni = 0; ni < 4; ++ni)
#pragma unroll
        for (int i = 0; i < 4; ++i) {
          const int m = m0 + mi * 16 + lh * 4 + i;
          const int e = n0 + ni * 16 + lr;
          outf[(size_t)m * N + e] = acc[mi][ni][i] + bias[e];
        }
  } else if (vswap) {
    // acc[mi][ni][i] = C^T[e][m]: e = n0+ni*16+lh*4+i, m = m0+mi*16+lr
#pragma unroll
    for (int mi = 0; mi < 4; ++mi)
#pragma unroll
      for (int ni = 0; ni < 4; ++ni)
#pragma unroll
        for (int i = 0; i < 4; ++i) {
          const int e = n0 + ni * 16 + lh * 4 + i;
          const int m = m0 + mi * 16 + lr;
          const int ecol = e & (DMODEL - 1);
          const int b = m >> 11, n = m & (S_LEN - 1);
          const int h = ecol >> 6, d = ecol & (HDIM - 1);
          (outb + 2 * XN)[((size_t)((b * NHEAD + h) * HDIM + d)) * S_LEN + n] =
              f2bf(acc[mi][ni][i]);
        }
  } else {  // Q/K thirds
    const int sel = tn >> 3;
#pragma unroll
    for (int mi = 0; mi < 4; ++mi)
#pragma unroll
      for (int ni = 0; ni < 4; ++ni)
#pragma unroll
        for (int i = 0; i < 4; ++i) {
          const int m = m0 + mi * 16 + lh * 4 + i;
          const int e = n0 + ni * 16 + lr;
          const int ecol = e & (DMODEL - 1);
          const int b = m >> 11, n = m & (S_LEN - 1);
          const int h = ecol >> 6, d = ecol & (HDIM - 1);
          if (sel == 0)
            outb[((size_t)((b * NHEAD + h) * S_LEN + n)) * HDIM + d] =
                f2bf(acc[mi][ni][i] * QSCALE);
          else
            (outb + XN)[((size_t)((b * NHEAD + h) * S_LEN + n)) * HDIM + d] =
                f2bf(acc[mi][ni][i]);
        }
  }
}

// ---- flash attention: 4-way intra-block KV-split, wave-private dbuf KV, m==0 softmax --
// (R11-verified, unchanged.)
__global__ __launch_bounds__(256) void attn_kernel(const short* __restrict__ Qg,
                                                   const short* __restrict__ Kg,
                                                   const short* __restrict__ Vg,
                                                   short* __restrict__ ctx) {
  __shared__ alignas(16) short KV[4][8192];  // per wave: K dbuf 2x2048 | V dbuf 2x2048
  __shared__ float mls[4][32];
  const int tidx = threadIdx.x;
  const int s = tidx >> 6;  // wave 0..3
  const int l = tidx & 63;
  const int lq = l & 31;
  const int h5 = l >> 5;
  const int bid = blockIdx.x;
  const int xcd = bid & 7;
  const int j = bid >> 3;             // 0..255 per-XCD stream index
  const int bh = xcd * 4 + (j >> 6);  // 4 heads per XCD -> K/V L2-resident
  const int qi = 63 - (j & 63);       // big blocks first (LPT under queueing)
  const int qbase = qi * 32;
  const short* Qh = Qg + (size_t)bh * (S_LEN * HDIM);
  const short* Kh = Kg + (size_t)bh * (S_LEN * HDIM);
  const short* Vh = Vg + (size_t)bh * (HDIM * S_LEN);

  short* Kbase = &KV[s][0];
  short* Vbase = &KV[s][4096];
  const int r8 = l >> 3;  // 0..7
  const int sc = l & 7;   // phys 16B slot this lane writes

  bf16x8 qf[4];
#pragma unroll
  for (int cc = 0; cc < 4; ++cc)
    qf[cc] = *(const bf16x8*)&Qh[(size_t)(qbase + lq) * HDIM + cc * 16 + h5 * 8];

  f32x16 o0 = {}, o1 = {};
  float ll = 0.f;

  const int ntot = qi + 1;
  const int ts = (ntot * s) >> 2;
  const int te = (ntot * (s + 1)) >> 2;

#define STAGE(T, BUF)                                                              \
  {                                                                                \
    _Pragma("unroll") for (int i = 0; i < 4; ++i) {                                \
      const int R = i * 8 + r8;                                                    \
      const int sg = sc ^ (R & 7);                                                 \
      GLL16(Kh + (size_t)((T)*32 + R) * HDIM + sg * 8,                             \
            &Kbase[(BUF)*2048 + i * 512]);                                         \
      GLL16(Vh + (size_t)(2 * R + (sg >> 2)) * S_LEN + (T)*32 + (sg & 3) * 8,      \
            &Vbase[(BUF)*2048 + i * 512]);                                         \
    }                                                                              \
  }

  if (ts < te) STAGE(ts, 0);

  for (int t = ts; t < te; ++t) {
    const int buf = (t - ts) & 1;
    if (t + 1 < te) {
      STAGE(t + 1, buf ^ 1);
      asm volatile("s_waitcnt vmcnt(8)" ::: "memory");
    } else {
      asm volatile("s_waitcnt vmcnt(0)" ::: "memory");
    }
    const short* Ksb = &Kbase[buf * 2048];
    const short* Vsb = &Vbase[buf * 2048];

    bf16x8 kf[4];
#pragma unroll
    for (int cc = 0; cc < 4; ++cc)
      kf[cc] = *(const bf16x8*)&Ksb[lq * 64 + 8 * ((cc * 2 + h5) ^ (lq & 7))];
    f32x16 st = {};
    __builtin_amdgcn_s_setprio(1);
#pragma unroll
    for (int cc = 0; cc < 4; ++cc) st = MFMA32(kf[cc], qf[cc], st);
    __builtin_amdgcn_s_setprio(0);

    if (t == qi) {
#pragma unroll
      for (int rr = 0; rr < 16; ++rr) {
        const int crow = (rr & 3) + 8 * (rr >> 2) + 4 * h5;
        if (crow > lq) st[rr] = -__builtin_inff();
      }
    }

#pragma unroll
    for (int rr = 0; rr < 16; ++rr) {
      st[rr] = __builtin_amdgcn_exp2f(st[rr]);
      ll += st[rr];
    }

    unsigned a0 = cvt_pk_bf16(st[0], st[1]), b0 = cvt_pk_bf16(st[4], st[5]);
    unsigned a1 = cvt_pk_bf16(st[2], st[3]), b1 = cvt_pk_bf16(st[6], st[7]);
    unsigned a2 = cvt_pk_bf16(st[8], st[9]), b2 = cvt_pk_bf16(st[12], st[13]);
    unsigned a3 = cvt_pk_bf16(st[10], st[11]), b3 = cvt_pk_bf16(st[14], st[15]);
    swap32(a0, b0);
    swap32(a1, b1);
    swap32(a2, b2);
    swap32(a3, b3);
    const u32x4 pw0 = {a0, a1, b0, b1};
    const u32x4 pw1 = {a2, a3, b2, b3};
    const bf16x8 pa0 = __builtin_bit_cast(bf16x8, pw0);
    const bf16x8 pa1 = __builtin_bit_cast(bf16x8, pw1);

    const int R0 = lq >> 1, p0 = (lq & 1) * 4 + h5;
    const int R1 = 16 + (lq >> 1);
    const bf16x8 v00 = *(const bf16x8*)&Vsb[R0 * 64 + 8 * ((p0 + 0) ^ (R0 & 7))];
    const bf16x8 v01 = *(const bf16x8*)&Vsb[R0 * 64 + 8 * ((p0 + 2) ^ (R0 & 7))];
    const bf16x8 v10 = *(const bf16x8*)&Vsb[R1 * 64 + 8 * ((p0 + 0) ^ (R1 & 7))];
    const bf16x8 v11 = *(const bf16x8*)&Vsb[R1 * 64 + 8 * ((p0 + 2) ^ (R1 & 7))];
    __builtin_amdgcn_s_setprio(1);
    o0 = MFMA32(pa0, v00, o0);
    o1 = MFMA32(pa0, v10, o1);
    o0 = MFMA32(pa1, v01, o0);
    o1 = MFMA32(pa1, v11, o1);
    __builtin_amdgcn_s_setprio(0);
  }
#undef STAGE

  float* me = (float*)&KV[s][0];
#pragma unroll
  for (int rr = 0; rr < 16; ++rr) {
    const int crow = (rr & 3) + 8 * (rr >> 2) + 4 * h5;
    me[crow * 64 + lq] = o0[rr];
    me[crow * 64 + 32 + lq] = o1[rr];
  }
  ll += __shfl_xor(ll, 32);
  if (h5 == 0) mls[s][lq] = ll;
  __syncthreads();

  const float* om0 = (const float*)&KV[0][0];
  const float* om1 = (const float*)&KV[1][0];
  const float* om2 = (const float*)&KV[2][0];
  const float* om3 = (const float*)&KV[3][0];
  const int b = bh >> 4, h = bh & (NHEAD - 1);
  const int r2 = tidx >> 3;
  const int d0 = (tidx & 7) * 8;
  const float inv =
      __builtin_amdgcn_rcpf(mls[0][r2] + mls[1][r2] + mls[2][r2] + mls[3][r2]);
  const size_t base = (size_t)(b * S_LEN + qbase + r2) * DMODEL + h * HDIM + d0;
#pragma unroll
  for (int i = 0; i < 8; ++i) {
    const int o = r2 * 64 + d0 + i;
    const float v = (om0[o] + om1[o] + om2[o] + om3[o]) * inv;
    ctx[base + i] = f2bf(v);
  }
}

extern "C" void kernel_launch(void* const* d_in, const int* in_sizes, int n_in,
                              void* d_out, int out_size, void* d_ws, size_t ws_size,
                              hipStream_t stream) {
  const float* x = (const float*)d_in[0];
  const float* Wq = (const float*)d_in[1];
  const float* Wk = (const float*)d_in[2];
  const float* Wv = (const float*)d_in[3];
  const float* Wo = (const float*)d_in[4];
  const float* bo = (const float*)d_in[5];

  const size_t XN = (size_t)MROWS * DMODEL;   // 4096*1024
  const size_t WN = (size_t)DMODEL * DMODEL;  // 1024*1024

  short* ws = (short*)d_ws;
  short* xb = ws;
  short* Wqb = xb + XN;  // Wq,Wk,Wv,Wo contiguous ([3072+1024][1024])
  short* Wob = Wqb + 3 * WN;
  short* Qb = Wob + WN;  // Q,K,V contiguous
  short* Kb = Qb + XN;
  short* Vb = Kb + XN;
  short* ctxb = Vb + XN;
  if (ws_size < (5 * XN + 4 * WN) * sizeof(short)) return;

  cvt_kernel<<<2048, 256, 0, stream>>>(x, xb, (int)XN);
  cvt_w4<<<dim3(256, 4), 256, 0, stream>>>(Wq, Wk, Wv, Wo, Wqb);

  gemm_bt<<<dim3(MROWS / 128, 3 * DMODEL / 128), 256, 0, stream>>>(xb, Wqb, Qb, nullptr,
                                                                   nullptr, 4);

  attn_kernel<<<2048, 256, 0, stream>>>(Qb, Kb, Vb, ctxb);

  gemm_bt<<<dim3(MROWS / 128, DMODEL / 128), 256, 0, stream>>>(ctxb, Wob, nullptr,
                                                               (float*)d_out, bo, 3);
}

// Round 14
// 125.689 us; speedup vs baseline: 1.0952x; 1.0952x over previous
//
#include <hip/hip_runtime.h>

#define DEV __device__ __forceinline__

typedef __bf16 bf16x8 __attribute__((ext_vector_type(8)));
typedef float f32x4 __attribute__((ext_vector_type(4)));
typedef float f32x16 __attribute__((ext_vector_type(16)));
typedef unsigned u32x4 __attribute__((ext_vector_type(4)));

constexpr int S_LEN = 2048;
constexpr int DMODEL = 1024;
constexpr int NHEAD = 16;
constexpr int HDIM = 64;
constexpr int BATCH = 2;
constexpr int MROWS = BATCH * S_LEN;  // 4096
constexpr float QSCALE = 0.125f * 1.44269504088896f;  // 1/sqrt(64) * log2(e)

DEV short f2bf(float x) {
  unsigned u = __builtin_bit_cast(unsigned, x);
  unsigned r = u + 0x7fffu + ((u >> 16) & 1u);
  return (short)(r >> 16);
}

#define MFMA16(a, b, c) __builtin_amdgcn_mfma_f32_16x16x32_bf16((a), (b), (c), 0, 0, 0)
#define MFMA32(a, b, c) __builtin_amdgcn_mfma_f32_32x32x16_bf16((a), (b), (c), 0, 0, 0)
#define GLL16(g, l)                                                                     \
  __builtin_amdgcn_global_load_lds((const __attribute__((address_space(1))) void*)(g),  \
                                   (__attribute__((address_space(3))) void*)(l), 16, 0, 0)

DEV unsigned cvt_pk_bf16(float a, float b) {
  unsigned r;
  asm("v_cvt_pk_bf16_f32 %0, %1, %2" : "=v"(r) : "v"(a), "v"(b));
  return r;
}
DEV void swap32(unsigned& a, unsigned& b) {
  asm("v_permlane32_swap_b32 %0, %1" : "+v"(a), "+v"(b));
}

// ---------------- fp32 -> bf16 converts ----------------
__global__ void cvt_kernel(const float* __restrict__ in, short* __restrict__ out, int n) {
  int i = (blockIdx.x * blockDim.x + threadIdx.x) * 4;
  const int stride = gridDim.x * blockDim.x * 4;
  for (; i < n; i += stride) {
    float4 v = *(const float4*)&in[i];
    short4 r;
    r.x = f2bf(v.x);
    r.y = f2bf(v.y);
    r.z = f2bf(v.z);
    r.w = f2bf(v.w);
    *(short4*)&out[i] = r;
  }
}

__global__ void cvt_w4(const float* __restrict__ Wq, const float* __restrict__ Wk,
                       const float* __restrict__ Wv, const float* __restrict__ Wo,
                       short* __restrict__ out) {
  const float* src = blockIdx.y == 0 ? Wq : blockIdx.y == 1 ? Wk : blockIdx.y == 2 ? Wv : Wo;
  short* dst = out + (size_t)blockIdx.y * (DMODEL * DMODEL);
  int i = (blockIdx.x * blockDim.x + threadIdx.x) * 4;
  const int stride = gridDim.x * blockDim.x * 4;
  for (; i < DMODEL * DMODEL; i += stride) {
    float4 v = *(const float4*)&src[i];
    short4 r;
    r.x = f2bf(v.x);
    r.y = f2bf(v.y);
    r.z = f2bf(v.z);
    r.w = f2bf(v.w);
    *(short4*)&dst[i] = r;
  }
}

// ---------------- QKV GEMM (R12-proven): 128x128, BK=64, 2-phase dbuf ----------------
// XOR-swizzled LDS (pre-swizzled global src + swizzled ds_read).
// mode 4 epilogue; V third (tn>=16) uses SWAPPED mfma(Wv,x) -> C^T, contiguous V^T store.
__global__ __launch_bounds__(256) void gemm_bt(const short* __restrict__ A,
                                               const short* __restrict__ Bt,
                                               short* __restrict__ outb) {
  constexpr int K = DMODEL;
  constexpr size_t XN = (size_t)MROWS * DMODEL;
  __shared__ short As[2][128 * 64];  // 32KB
  __shared__ short Bs[2][128 * 64];  // 32KB
  const int tid = threadIdx.x;
  const int w = tid >> 6, l = tid & 63;
  const int lr = l & 15, lh = l >> 4;
  const int wr = w >> 1, wc = w & 1;
  const int tm = blockIdx.x, tn = blockIdx.y;
  const bool vswap = (tn >= 16);

  const int srow = tid >> 3;         // 0..31 within round
  const int ssl = tid & 7;           // LDS slot
  const int ssg = ssl ^ (srow & 7);  // pre-swizzled global 16B column

  f32x4 acc[4][4] = {};

#define GSTAGE(KT, BUF)                                                             \
  {                                                                                 \
    _Pragma("unroll") for (int i = 0; i < 4; ++i) {                                 \
      const int row = i * 32 + srow;                                                \
      GLL16(A + (size_t)(tm * 128 + row) * K + (KT)*64 + ssg * 8,                   \
            &As[BUF][(i * 256 + w * 64) * 8]);                                      \
    }                                                                               \
    _Pragma("unroll") for (int i = 0; i < 4; ++i) {                                 \
      const int row = i * 32 + srow;                                                \
      GLL16(Bt + (size_t)(tn * 128 + row) * K + (KT)*64 + ssg * 8,                  \
            &Bs[BUF][(i * 256 + w * 64) * 8]);                                      \
    }                                                                               \
  }

  GSTAGE(0, 0);
  asm volatile("s_waitcnt vmcnt(0)" ::: "memory");
  __syncthreads();

  for (int kt = 0; kt < K / 64; ++kt) {
    const int buf = kt & 1;
    if (kt < K / 64 - 1) GSTAGE(kt + 1, buf ^ 1);  // issue early; hides under MFMA

#pragma unroll
    for (int kh = 0; kh < 2; ++kh) {
      bf16x8 af[4], bfr[4];
#pragma unroll
      for (int mi = 0; mi < 4; ++mi) {
        const int row = wr * 64 + mi * 16 + lr;
        af[mi] = *(const bf16x8*)&As[buf][row * 64 + 8 * ((kh * 4 + lh) ^ (row & 7))];
      }
#pragma unroll
      for (int ni = 0; ni < 4; ++ni) {
        const int row = wc * 64 + ni * 16 + lr;
        bfr[ni] = *(const bf16x8*)&Bs[buf][row * 64 + 8 * ((kh * 4 + lh) ^ (row & 7))];
      }
      if (vswap) {
#pragma unroll
        for (int mi = 0; mi < 4; ++mi)
#pragma unroll
          for (int ni = 0; ni < 4; ++ni)
            acc[mi][ni] = MFMA16(bfr[ni], af[mi], acc[mi][ni]);
      } else {
#pragma unroll
        for (int mi = 0; mi < 4; ++mi)
#pragma unroll
          for (int ni = 0; ni < 4; ++ni)
            acc[mi][ni] = MFMA16(af[mi], bfr[ni], acc[mi][ni]);
      }
    }

    asm volatile("s_waitcnt vmcnt(0)" ::: "memory");
    __syncthreads();
  }
#undef GSTAGE

  const int m0 = tm * 128 + wr * 64;
  const int n0 = tn * 128 + wc * 64;
  if (vswap) {
    // acc[mi][ni][i] = C^T[e][m]: e = n0+ni*16+lh*4+i, m = m0+mi*16+lr
#pragma unroll
    for (int mi = 0; mi < 4; ++mi)
#pragma unroll
      for (int ni = 0; ni < 4; ++ni)
#pragma unroll
        for (int i = 0; i < 4; ++i) {
          const int e = n0 + ni * 16 + lh * 4 + i;
          const int m = m0 + mi * 16 + lr;
          const int ecol = e & (DMODEL - 1);
          const int b = m >> 11, n = m & (S_LEN - 1);
          const int h = ecol >> 6, d = ecol & (HDIM - 1);
          (outb + 2 * XN)[((size_t)((b * NHEAD + h) * HDIM + d)) * S_LEN + n] =
              f2bf(acc[mi][ni][i]);
        }
  } else {  // Q/K thirds
    const int sel = tn >> 3;
#pragma unroll
    for (int mi = 0; mi < 4; ++mi)
#pragma unroll
      for (int ni = 0; ni < 4; ++ni)
#pragma unroll
        for (int i = 0; i < 4; ++i) {
          const int m = m0 + mi * 16 + lh * 4 + i;
          const int e = n0 + ni * 16 + lr;
          const int ecol = e & (DMODEL - 1);
          const int b = m >> 11, n = m & (S_LEN - 1);
          const int h = ecol >> 6, d = ecol & (HDIM - 1);
          if (sel == 0)
            outb[((size_t)((b * NHEAD + h) * S_LEN + n)) * HDIM + d] =
                f2bf(acc[mi][ni][i] * QSCALE);
          else
            (outb + XN)[((size_t)((b * NHEAD + h) * S_LEN + n)) * HDIM + d] =
                f2bf(acc[mi][ni][i]);
        }
  }
}

// ---------------- out-proj GEMM: 64x128 tile -> 512 blocks (2/CU) ----------------
// BK=64 2-phase dbuf, full-XOR swizzle. 4 waves over N (wave tile 64x32).
// out = fp32 [M][N] + bias.
__global__ __launch_bounds__(256) void gemm_out(const short* __restrict__ A,
                                                const short* __restrict__ Bt,
                                                float* __restrict__ outf,
                                                const float* __restrict__ bias) {
  constexpr int K = DMODEL;
  constexpr int N = DMODEL;
  __shared__ short As[2][64 * 64];   // 8KB x2
  __shared__ short Bs[2][128 * 64];  // 16KB x2
  const int tid = threadIdx.x;
  const int w = tid >> 6, l = tid & 63;
  const int lr = l & 15, lh = l >> 4;
  const int wc = w;  // wave owns N columns wc*32..wc*32+31
  const int tm = blockIdx.x, tn = blockIdx.y;

  const int srow = tid >> 3;
  const int ssl = tid & 7;
  const int ssg = ssl ^ (srow & 7);

  f32x4 acc[4][2] = {};

#define OSTAGE(KT, BUF)                                                             \
  {                                                                                 \
    _Pragma("unroll") for (int i = 0; i < 2; ++i) {                                 \
      const int row = i * 32 + srow;                                                \
      GLL16(A + (size_t)(tm * 64 + row) * K + (KT)*64 + ssg * 8,                    \
            &As[BUF][(i * 256 + w * 64) * 8]);                                      \
    }                                                                               \
    _Pragma("unroll") for (int i = 0; i < 4; ++i) {                                 \
      const int row = i * 32 + srow;                                                \
      GLL16(Bt + (size_t)(tn * 128 + row) * K + (KT)*64 + ssg * 8,                  \
            &Bs[BUF][(i * 256 + w * 64) * 8]);                                      \
    }                                                                               \
  }

  OSTAGE(0, 0);
  asm volatile("s_waitcnt vmcnt(0)" ::: "memory");
  __syncthreads();

  for (int kt = 0; kt < K / 64; ++kt) {
    const int buf = kt & 1;
    if (kt < K / 64 - 1) OSTAGE(kt + 1, buf ^ 1);

#pragma unroll
    for (int kh = 0; kh < 2; ++kh) {
      bf16x8 af[4], bfr[2];
#pragma unroll
      for (int mi = 0; mi < 4; ++mi) {
        const int row = mi * 16 + lr;
        af[mi] = *(const bf16x8*)&As[buf][row * 64 + 8 * ((kh * 4 + lh) ^ (row & 7))];
      }
#pragma unroll
      for (int ni = 0; ni < 2; ++ni) {
        const int row = wc * 32 + ni * 16 + lr;
        bfr[ni] = *(const bf16x8*)&Bs[buf][row * 64 + 8 * ((kh * 4 + lh) ^ (row & 7))];
      }
#pragma unroll
      for (int mi = 0; mi < 4; ++mi)
#pragma unroll
        for (int ni = 0; ni < 2; ++ni)
          acc[mi][ni] = MFMA16(af[mi], bfr[ni], acc[mi][ni]);
    }

    asm volatile("s_waitcnt vmcnt(0)" ::: "memory");
    __syncthreads();
  }
#undef OSTAGE

#pragma unroll
  for (int mi = 0; mi < 4; ++mi)
#pragma unroll
    for (int ni = 0; ni < 2; ++ni)
#pragma unroll
      for (int i = 0; i < 4; ++i) {
        const int m = tm * 64 + mi * 16 + lh * 4 + i;
        const int e = tn * 128 + wc * 32 + ni * 16 + lr;
        outf[(size_t)m * N + e] = acc[mi][ni][i] + bias[e];
      }
}

// ---- flash attention: 8-way intra-block KV-split, wave-private dbuf KV, m==0 softmax --
// Block = 512 thr (8 waves) on ONE 32-row q-chunk. Wave s takes tiles
// [ntot*s/8, ntot*(s+1)/8). Longest serial chain: 16 -> 8 tiles. LDS 129KB -> 1
// block/CU resident + 7-deep queue (dynamic LPT, big-qi first). Merge = plain sum
// (m==0): wave s writes 8KB f32 partials over ITS OWN K-dbuf region (R10-verified).
__global__ __launch_bounds__(512) void attn_kernel(const short* __restrict__ Qg,
                                                   const short* __restrict__ Kg,
                                                   const short* __restrict__ Vg,
                                                   short* __restrict__ ctx) {
  __shared__ alignas(16) short KV[8][8192];  // per wave: K dbuf 2x2048 | V dbuf 2x2048
  __shared__ float mls[8][32];
  const int tidx = threadIdx.x;
  const int s = tidx >> 6;  // wave 0..7
  const int l = tidx & 63;
  const int lq = l & 31;
  const int h5 = l >> 5;
  const int bid = blockIdx.x;
  const int xcd = bid & 7;
  const int j = bid >> 3;             // 0..255 per-XCD stream index
  const int bh = xcd * 4 + (j >> 6);  // 4 heads per XCD -> K/V L2-resident
  const int qi = 63 - (j & 63);       // big blocks first (LPT under queueing)
  const int qbase = qi * 32;
  const short* Qh = Qg + (size_t)bh * (S_LEN * HDIM);
  const short* Kh = Kg + (size_t)bh * (S_LEN * HDIM);
  const short* Vh = Vg + (size_t)bh * (HDIM * S_LEN);

  short* Kbase = &KV[s][0];
  short* Vbase = &KV[s][4096];
  const int r8 = l >> 3;
  const int sc = l & 7;

  bf16x8 qf[4];
#pragma unroll
  for (int cc = 0; cc < 4; ++cc)
    qf[cc] = *(const bf16x8*)&Qh[(size_t)(qbase + lq) * HDIM + cc * 16 + h5 * 8];

  f32x16 o0 = {}, o1 = {};
  float ll = 0.f;

  const int ntot = qi + 1;
  const int ts = (ntot * s) >> 3;
  const int te = (ntot * (s + 1)) >> 3;

#define STAGE(T, BUF)                                                              \
  {                                                                                \
    _Pragma("unroll") for (int i = 0; i < 4; ++i) {                                \
      const int R = i * 8 + r8;                                                    \
      const int sg = sc ^ (R & 7);                                                 \
      GLL16(Kh + (size_t)((T)*32 + R) * HDIM + sg * 8,                             \
            &Kbase[(BUF)*2048 + i * 512]);                                         \
      GLL16(Vh + (size_t)(2 * R + (sg >> 2)) * S_LEN + (T)*32 + (sg & 3) * 8,      \
            &Vbase[(BUF)*2048 + i * 512]);                                         \
    }                                                                              \
  }

  if (ts < te) STAGE(ts, 0);

  for (int t = ts; t < te; ++t) {
    const int buf = (t - ts) & 1;
    if (t + 1 < te) {
      STAGE(t + 1, buf ^ 1);
      asm volatile("s_waitcnt vmcnt(8)" ::: "memory");
    } else {
      asm volatile("s_waitcnt vmcnt(0)" ::: "memory");
    }
    const short* Ksb = &Kbase[buf * 2048];
    const short* Vsb = &Vbase[buf * 2048];

    bf16x8 kf[4];
#pragma unroll
    for (int cc = 0; cc < 4; ++cc)
      kf[cc] = *(const bf16x8*)&Ksb[lq * 64 + 8 * ((cc * 2 + h5) ^ (lq & 7))];
    f32x16 st = {};
    __builtin_amdgcn_s_setprio(1);
#pragma unroll
    for (int cc = 0; cc < 4; ++cc) st = MFMA32(kf[cc], qf[cc], st);
    __builtin_amdgcn_s_setprio(0);

    if (t == qi) {
#pragma unroll
      for (int rr = 0; rr < 16; ++rr) {
        const int crow = (rr & 3) + 8 * (rr >> 2) + 4 * h5;
        if (crow > lq) st[rr] = -__builtin_inff();
      }
    }

#pragma unroll
    for (int rr = 0; rr < 16; ++rr) {
      st[rr] = __builtin_amdgcn_exp2f(st[rr]);
      ll += st[rr];
    }

    unsigned a0 = cvt_pk_bf16(st[0], st[1]), b0 = cvt_pk_bf16(st[4], st[5]);
    unsigned a1 = cvt_pk_bf16(st[2], st[3]), b1 = cvt_pk_bf16(st[6], st[7]);
    unsigned a2 = cvt_pk_bf16(st[8], st[9]), b2 = cvt_pk_bf16(st[12], st[13]);
    unsigned a3 = cvt_pk_bf16(st[10], st[11]), b3 = cvt_pk_bf16(st[14], st[15]);
    swap32(a0, b0);
    swap32(a1, b1);
    swap32(a2, b2);
    swap32(a3, b3);
    const u32x4 pw0 = {a0, a1, b0, b1};
    const u32x4 pw1 = {a2, a3, b2, b3};
    const bf16x8 pa0 = __builtin_bit_cast(bf16x8, pw0);
    const bf16x8 pa1 = __builtin_bit_cast(bf16x8, pw1);

    const int R0 = lq >> 1, p0 = (lq & 1) * 4 + h5;
    const int R1 = 16 + (lq >> 1);
    const bf16x8 v00 = *(const bf16x8*)&Vsb[R0 * 64 + 8 * ((p0 + 0) ^ (R0 & 7))];
    const bf16x8 v01 = *(const bf16x8*)&Vsb[R0 * 64 + 8 * ((p0 + 2) ^ (R0 & 7))];
    const bf16x8 v10 = *(const bf16x8*)&Vsb[R1 * 64 + 8 * ((p0 + 0) ^ (R1 & 7))];
    const bf16x8 v11 = *(const bf16x8*)&Vsb[R1 * 64 + 8 * ((p0 + 2) ^ (R1 & 7))];
    __builtin_amdgcn_s_setprio(1);
    o0 = MFMA32(pa0, v00, o0);
    o1 = MFMA32(pa0, v10, o1);
    o0 = MFMA32(pa1, v01, o0);
    o1 = MFMA32(pa1, v11, o1);
    __builtin_amdgcn_s_setprio(0);
  }
#undef STAGE

  // wave s writes partials over ITS OWN K-dbuf region (8KB = 2048 floats) — disjoint.
  float* me = (float*)&KV[s][0];
#pragma unroll
  for (int rr = 0; rr < 16; ++rr) {
    const int crow = (rr & 3) + 8 * (rr >> 2) + 4 * h5;
    me[crow * 64 + lq] = o0[rr];
    me[crow * 64 + 32 + lq] = o1[rr];
  }
  ll += __shfl_xor(ll, 32);
  if (h5 == 0) mls[s][lq] = ll;
  __syncthreads();

  const float* om = (const float*)&KV[0][0];  // stride 4096 floats between waves
  const int b = bh >> 4, h = bh & (NHEAD - 1);
  const int r2 = tidx >> 4;       // q-row 0..31
  const int d0 = (tidx & 15) * 4; // d group (4 elems)
  float lsum = 0.f;
#pragma unroll
  for (int ss = 0; ss < 8; ++ss) lsum += mls[ss][r2];
  const float inv = __builtin_amdgcn_rcpf(lsum);
  const size_t base = (size_t)(b * S_LEN + qbase + r2) * DMODEL + h * HDIM + d0;
#pragma unroll
  for (int i = 0; i < 4; ++i) {
    const int o = r2 * 64 + d0 + i;
    float v = 0.f;
#pragma unroll
    for (int ss = 0; ss < 8; ++ss) v += om[ss * 4096 + o];
    ctx[base + i] = f2bf(v * inv);
  }
}

extern "C" void kernel_launch(void* const* d_in, const int* in_sizes, int n_in,
                              void* d_out, int out_size, void* d_ws, size_t ws_size,
                              hipStream_t stream) {
  const float* x = (const float*)d_in[0];
  const float* Wq = (const float*)d_in[1];
  const float* Wk = (const float*)d_in[2];
  const float* Wv = (const float*)d_in[3];
  const float* Wo = (const float*)d_in[4];
  const float* bo = (const float*)d_in[5];

  const size_t XN = (size_t)MROWS * DMODEL;   // 4096*1024
  const size_t WN = (size_t)DMODEL * DMODEL;  // 1024*1024

  short* ws = (short*)d_ws;
  short* xb = ws;
  short* Wqb = xb + XN;  // Wq,Wk,Wv,Wo contiguous ([3072+1024][1024])
  short* Wob = Wqb + 3 * WN;
  short* Qb = Wob + WN;  // Q,K,V contiguous
  short* Kb = Qb + XN;
  short* Vb = Kb + XN;
  short* ctxb = Vb + XN;
  if (ws_size < (5 * XN + 4 * WN) * sizeof(short)) return;

  cvt_kernel<<<2048, 256, 0, stream>>>(x, xb, (int)XN);
  cvt_w4<<<dim3(256, 4), 256, 0, stream>>>(Wq, Wk, Wv, Wo, Wqb);

  gemm_bt<<<dim3(MROWS / 128, 3 * DMODEL / 128), 256, 0, stream>>>(xb, Wqb, Qb);

  attn_kernel<<<2048, 512, 0, stream>>>(Qb, Kb, Vb, ctxb);

  gemm_out<<<dim3(MROWS / 64, DMODEL / 128), 256, 0, stream>>>(ctxb, Wob, (float*)d_out,
                                                               bo);
}

// Round 15
// 118.537 us; speedup vs baseline: 1.1613x; 1.0603x over previous
//
#include <hip/hip_runtime.h>

#define DEV __device__ __forceinline__

typedef __bf16 bf16x8 __attribute__((ext_vector_type(8)));
typedef float f32x4 __attribute__((ext_vector_type(4)));
typedef float f32x16 __attribute__((ext_vector_type(16)));
typedef unsigned u32x4 __attribute__((ext_vector_type(4)));

constexpr int S_LEN = 2048;
constexpr int DMODEL = 1024;
constexpr int NHEAD = 16;
constexpr int HDIM = 64;
constexpr int BATCH = 2;
constexpr int MROWS = BATCH * S_LEN;  // 4096
constexpr float QSCALE = 0.125f * 1.44269504088896f;  // 1/sqrt(64) * log2(e)

DEV short f2bf(float x) {
  unsigned u = __builtin_bit_cast(unsigned, x);
  unsigned r = u + 0x7fffu + ((u >> 16) & 1u);
  return (short)(r >> 16);
}

#define MFMA16(a, b, c) __builtin_amdgcn_mfma_f32_16x16x32_bf16((a), (b), (c), 0, 0, 0)
#define MFMA32(a, b, c) __builtin_amdgcn_mfma_f32_32x32x16_bf16((a), (b), (c), 0, 0, 0)
#define GLL16(g, l)                                                                     \
  __builtin_amdgcn_global_load_lds((const __attribute__((address_space(1))) void*)(g),  \
                                   (__attribute__((address_space(3))) void*)(l), 16, 0, 0)

DEV unsigned cvt_pk_bf16(float a, float b) {
  unsigned r;
  asm("v_cvt_pk_bf16_f32 %0, %1, %2" : "=v"(r) : "v"(a), "v"(b));
  return r;
}
DEV void swap32(unsigned& a, unsigned& b) {
  asm("v_permlane32_swap_b32 %0, %1" : "+v"(a), "+v"(b));
}

// ---------------- fp32 -> bf16 converts ----------------
__global__ void cvt_kernel(const float* __restrict__ in, short* __restrict__ out, int n) {
  int i = (blockIdx.x * blockDim.x + threadIdx.x) * 4;
  const int stride = gridDim.x * blockDim.x * 4;
  for (; i < n; i += stride) {
    float4 v = *(const float4*)&in[i];
    short4 r;
    r.x = f2bf(v.x);
    r.y = f2bf(v.y);
    r.z = f2bf(v.z);
    r.w = f2bf(v.w);
    *(short4*)&out[i] = r;
  }
}

__global__ void cvt_w4(const float* __restrict__ Wq, const float* __restrict__ Wk,
                       const float* __restrict__ Wv, const float* __restrict__ Wo,
                       short* __restrict__ out) {
  const float* src = blockIdx.y == 0 ? Wq : blockIdx.y == 1 ? Wk : blockIdx.y == 2 ? Wv : Wo;
  short* dst = out + (size_t)blockIdx.y * (DMODEL * DMODEL);
  int i = (blockIdx.x * blockDim.x + threadIdx.x) * 4;
  const int stride = gridDim.x * blockDim.x * 4;
  for (; i < DMODEL * DMODEL; i += stride) {
    float4 v = *(const float4*)&src[i];
    short4 r;
    r.x = f2bf(v.x);
    r.y = f2bf(v.y);
    r.z = f2bf(v.z);
    r.w = f2bf(v.w);
    *(short4*)&dst[i] = r;
  }
}

// ---------------- QKV GEMM (R14-proven): 128x128, BK=64, 2-phase dbuf ----------------
// XOR-swizzled LDS (pre-swizzled global src + swizzled ds_read).
// V third (tn>=16) uses SWAPPED mfma(Wv,x) -> C^T, contiguous V^T store.
__global__ __launch_bounds__(256) void gemm_bt(const short* __restrict__ A,
                                               const short* __restrict__ Bt,
                                               short* __restrict__ outb) {
  constexpr int K = DMODEL;
  constexpr size_t XN = (size_t)MROWS * DMODEL;
  __shared__ short As[2][128 * 64];  // 32KB
  __shared__ short Bs[2][128 * 64];  // 32KB
  const int tid = threadIdx.x;
  const int w = tid >> 6, l = tid & 63;
  const int lr = l & 15, lh = l >> 4;
  const int wr = w >> 1, wc = w & 1;
  const int tm = blockIdx.x, tn = blockIdx.y;
  const bool vswap = (tn >= 16);

  const int srow = tid >> 3;         // 0..31 within round
  const int ssl = tid & 7;           // LDS slot
  const int ssg = ssl ^ (srow & 7);  // pre-swizzled global 16B column

  f32x4 acc[4][4] = {};

#define GSTAGE(KT, BUF)                                                             \
  {                                                                                 \
    _Pragma("unroll") for (int i = 0; i < 4; ++i) {                                 \
      const int row = i * 32 + srow;                                                \
      GLL16(A + (size_t)(tm * 128 + row) * K + (KT)*64 + ssg * 8,                   \
            &As[BUF][(i * 256 + w * 64) * 8]);                                      \
    }                                                                               \
    _Pragma("unroll") for (int i = 0; i < 4; ++i) {                                 \
      const int row = i * 32 + srow;                                                \
      GLL16(Bt + (size_t)(tn * 128 + row) * K + (KT)*64 + ssg * 8,                  \
            &Bs[BUF][(i * 256 + w * 64) * 8]);                                      \
    }                                                                               \
  }

  GSTAGE(0, 0);
  asm volatile("s_waitcnt vmcnt(0)" ::: "memory");
  __syncthreads();

  for (int kt = 0; kt < K / 64; ++kt) {
    const int buf = kt & 1;
    if (kt < K / 64 - 1) GSTAGE(kt + 1, buf ^ 1);  // issue early; hides under MFMA

#pragma unroll
    for (int kh = 0; kh < 2; ++kh) {
      bf16x8 af[4], bfr[4];
#pragma unroll
      for (int mi = 0; mi < 4; ++mi) {
        const int row = wr * 64 + mi * 16 + lr;
        af[mi] = *(const bf16x8*)&As[buf][row * 64 + 8 * ((kh * 4 + lh) ^ (row & 7))];
      }
#pragma unroll
      for (int ni = 0; ni < 4; ++ni) {
        const int row = wc * 64 + ni * 16 + lr;
        bfr[ni] = *(const bf16x8*)&Bs[buf][row * 64 + 8 * ((kh * 4 + lh) ^ (row & 7))];
      }
      if (vswap) {
#pragma unroll
        for (int mi = 0; mi < 4; ++mi)
#pragma unroll
          for (int ni = 0; ni < 4; ++ni)
            acc[mi][ni] = MFMA16(bfr[ni], af[mi], acc[mi][ni]);
      } else {
#pragma unroll
        for (int mi = 0; mi < 4; ++mi)
#pragma unroll
          for (int ni = 0; ni < 4; ++ni)
            acc[mi][ni] = MFMA16(af[mi], bfr[ni], acc[mi][ni]);
      }
    }

    asm volatile("s_waitcnt vmcnt(0)" ::: "memory");
    __syncthreads();
  }
#undef GSTAGE

  const int m0 = tm * 128 + wr * 64;
  const int n0 = tn * 128 + wc * 64;
  if (vswap) {
    // acc[mi][ni][i] = C^T[e][m]: e = n0+ni*16+lh*4+i, m = m0+mi*16+lr
#pragma unroll
    for (int mi = 0; mi < 4; ++mi)
#pragma unroll
      for (int ni = 0; ni < 4; ++ni)
#pragma unroll
        for (int i = 0; i < 4; ++i) {
          const int e = n0 + ni * 16 + lh * 4 + i;
          const int m = m0 + mi * 16 + lr;
          const int ecol = e & (DMODEL - 1);
          const int b = m >> 11, n = m & (S_LEN - 1);
          const int h = ecol >> 6, d = ecol & (HDIM - 1);
          (outb + 2 * XN)[((size_t)((b * NHEAD + h) * HDIM + d)) * S_LEN + n] =
              f2bf(acc[mi][ni][i]);
        }
  } else {  // Q/K thirds
    const int sel = tn >> 3;
#pragma unroll
    for (int mi = 0; mi < 4; ++mi)
#pragma unroll
      for (int ni = 0; ni < 4; ++ni)
#pragma unroll
        for (int i = 0; i < 4; ++i) {
          const int m = m0 + mi * 16 + lh * 4 + i;
          const int e = n0 + ni * 16 + lr;
          const int ecol = e & (DMODEL - 1);
          const int b = m >> 11, n = m & (S_LEN - 1);
          const int h = ecol >> 6, d = ecol & (HDIM - 1);
          if (sel == 0)
            outb[((size_t)((b * NHEAD + h) * S_LEN + n)) * HDIM + d] =
                f2bf(acc[mi][ni][i] * QSCALE);
          else
            (outb + XN)[((size_t)((b * NHEAD + h) * S_LEN + n)) * HDIM + d] =
                f2bf(acc[mi][ni][i]);
        }
  }
}

// ---------------- out-proj GEMM (R14-proven): 64x128 tile -> 512 blocks (2/CU) -------
__global__ __launch_bounds__(256) void gemm_out(const short* __restrict__ A,
                                                const short* __restrict__ Bt,
                                                float* __restrict__ outf,
                                                const float* __restrict__ bias) {
  constexpr int K = DMODEL;
  constexpr int N = DMODEL;
  __shared__ short As[2][64 * 64];   // 8KB x2
  __shared__ short Bs[2][128 * 64];  // 16KB x2
  const int tid = threadIdx.x;
  const int w = tid >> 6, l = tid & 63;
  const int lr = l & 15, lh = l >> 4;
  const int wc = w;  // wave owns N columns wc*32..wc*32+31
  const int tm = blockIdx.x, tn = blockIdx.y;

  const int srow = tid >> 3;
  const int ssl = tid & 7;
  const int ssg = ssl ^ (srow & 7);

  f32x4 acc[4][2] = {};

#define OSTAGE(KT, BUF)                                                             \
  {                                                                                 \
    _Pragma("unroll") for (int i = 0; i < 2; ++i) {                                 \
      const int row = i * 32 + srow;                                                \
      GLL16(A + (size_t)(tm * 64 + row) * K + (KT)*64 + ssg * 8,                    \
            &As[BUF][(i * 256 + w * 64) * 8]);                                      \
    }                                                                               \
    _Pragma("unroll") for (int i = 0; i < 4; ++i) {                                 \
      const int row = i * 32 + srow;                                                \
      GLL16(Bt + (size_t)(tn * 128 + row) * K + (KT)*64 + ssg * 8,                  \
            &Bs[BUF][(i * 256 + w * 64) * 8]);                                      \
    }                                                                               \
  }

  OSTAGE(0, 0);
  asm volatile("s_waitcnt vmcnt(0)" ::: "memory");
  __syncthreads();

  for (int kt = 0; kt < K / 64; ++kt) {
    const int buf = kt & 1;
    if (kt < K / 64 - 1) OSTAGE(kt + 1, buf ^ 1);

#pragma unroll
    for (int kh = 0; kh < 2; ++kh) {
      bf16x8 af[4], bfr[2];
#pragma unroll
      for (int mi = 0; mi < 4; ++mi) {
        const int row = mi * 16 + lr;
        af[mi] = *(const bf16x8*)&As[buf][row * 64 + 8 * ((kh * 4 + lh) ^ (row & 7))];
      }
#pragma unroll
      for (int ni = 0; ni < 2; ++ni) {
        const int row = wc * 32 + ni * 16 + lr;
        bfr[ni] = *(const bf16x8*)&Bs[buf][row * 64 + 8 * ((kh * 4 + lh) ^ (row & 7))];
      }
#pragma unroll
      for (int mi = 0; mi < 4; ++mi)
#pragma unroll
        for (int ni = 0; ni < 2; ++ni)
          acc[mi][ni] = MFMA16(af[mi], bfr[ni], acc[mi][ni]);
    }

    asm volatile("s_waitcnt vmcnt(0)" ::: "memory");
    __syncthreads();
  }
#undef OSTAGE

#pragma unroll
  for (int mi = 0; mi < 4; ++mi)
#pragma unroll
    for (int ni = 0; ni < 2; ++ni)
#pragma unroll
      for (int i = 0; i < 4; ++i) {
        const int m = tm * 64 + mi * 16 + lh * 4 + i;
        const int e = tn * 128 + wc * 32 + ni * 16 + lr;
        outf[(size_t)m * N + e] = acc[mi][ni][i] + bias[e];
      }
}

// ---- flash attention (R11-proven): 4-way intra-block KV-split, wave-private dbuf KV --
// Block = 256 thr (4 waves) on ONE 32-row q-chunk; wave s takes tiles
// [ntot*s/4, ntot*(s+1)/4). LDS 64.5KB -> 2 blocks/CU resident + queue (LPT big-qi
// first). m==0 fixed-shift softmax; merge = plain sum over own-K-dbuf partials.
__global__ __launch_bounds__(256) void attn_kernel(const short* __restrict__ Qg,
                                                   const short* __restrict__ Kg,
                                                   const short* __restrict__ Vg,
                                                   short* __restrict__ ctx) {
  __shared__ alignas(16) short KV[4][8192];  // per wave: K dbuf 2x2048 | V dbuf 2x2048
  __shared__ float mls[4][32];
  const int tidx = threadIdx.x;
  const int s = tidx >> 6;  // wave 0..3
  const int l = tidx & 63;
  const int lq = l & 31;
  const int h5 = l >> 5;
  const int bid = blockIdx.x;
  const int xcd = bid & 7;
  const int j = bid >> 3;             // 0..255 per-XCD stream index
  const int bh = xcd * 4 + (j >> 6);  // 4 heads per XCD -> K/V L2-resident
  const int qi = 63 - (j & 63);       // big blocks first (LPT under queueing)
  const int qbase = qi * 32;
  const short* Qh = Qg + (size_t)bh * (S_LEN * HDIM);
  const short* Kh = Kg + (size_t)bh * (S_LEN * HDIM);
  const short* Vh = Vg + (size_t)bh * (HDIM * S_LEN);

  short* Kbase = &KV[s][0];
  short* Vbase = &KV[s][4096];
  const int r8 = l >> 3;
  const int sc = l & 7;

  bf16x8 qf[4];
#pragma unroll
  for (int cc = 0; cc < 4; ++cc)
    qf[cc] = *(const bf16x8*)&Qh[(size_t)(qbase + lq) * HDIM + cc * 16 + h5 * 8];

  f32x16 o0 = {}, o1 = {};
  float ll = 0.f;

  const int ntot = qi + 1;
  const int ts = (ntot * s) >> 2;
  const int te = (ntot * (s + 1)) >> 2;

#define STAGE(T, BUF)                                                              \
  {                                                                                \
    _Pragma("unroll") for (int i = 0; i < 4; ++i) {                                \
      const int R = i * 8 + r8;                                                    \
      const int sg = sc ^ (R & 7);                                                 \
      GLL16(Kh + (size_t)((T)*32 + R) * HDIM + sg * 8,                             \
            &Kbase[(BUF)*2048 + i * 512]);                                         \
      GLL16(Vh + (size_t)(2 * R + (sg >> 2)) * S_LEN + (T)*32 + (sg & 3) * 8,      \
            &Vbase[(BUF)*2048 + i * 512]);                                         \
    }                                                                              \
  }

  if (ts < te) STAGE(ts, 0);

  for (int t = ts; t < te; ++t) {
    const int buf = (t - ts) & 1;
    if (t + 1 < te) {
      STAGE(t + 1, buf ^ 1);
      asm volatile("s_waitcnt vmcnt(8)" ::: "memory");
    } else {
      asm volatile("s_waitcnt vmcnt(0)" ::: "memory");
    }
    const short* Ksb = &Kbase[buf * 2048];
    const short* Vsb = &Vbase[buf * 2048];

    bf16x8 kf[4];
#pragma unroll
    for (int cc = 0; cc < 4; ++cc)
      kf[cc] = *(const bf16x8*)&Ksb[lq * 64 + 8 * ((cc * 2 + h5) ^ (lq & 7))];
    f32x16 st = {};
    __builtin_amdgcn_s_setprio(1);
#pragma unroll
    for (int cc = 0; cc < 4; ++cc) st = MFMA32(kf[cc], qf[cc], st);
    __builtin_amdgcn_s_setprio(0);

    if (t == qi) {
#pragma unroll
      for (int rr = 0; rr < 16; ++rr) {
        const int crow = (rr & 3) + 8 * (rr >> 2) + 4 * h5;
        if (crow > lq) st[rr] = -__builtin_inff();
      }
    }

#pragma unroll
    for (int rr = 0; rr < 16; ++rr) {
      st[rr] = __builtin_amdgcn_exp2f(st[rr]);
      ll += st[rr];
    }

    unsigned a0 = cvt_pk_bf16(st[0], st[1]), b0 = cvt_pk_bf16(st[4], st[5]);
    unsigned a1 = cvt_pk_bf16(st[2], st[3]), b1 = cvt_pk_bf16(st[6], st[7]);
    unsigned a2 = cvt_pk_bf16(st[8], st[9]), b2 = cvt_pk_bf16(st[12], st[13]);
    unsigned a3 = cvt_pk_bf16(st[10], st[11]), b3 = cvt_pk_bf16(st[14], st[15]);
    swap32(a0, b0);
    swap32(a1, b1);
    swap32(a2, b2);
    swap32(a3, b3);
    const u32x4 pw0 = {a0, a1, b0, b1};
    const u32x4 pw1 = {a2, a3, b2, b3};
    const bf16x8 pa0 = __builtin_bit_cast(bf16x8, pw0);
    const bf16x8 pa1 = __builtin_bit_cast(bf16x8, pw1);

    const int R0 = lq >> 1, p0 = (lq & 1) * 4 + h5;
    const int R1 = 16 + (lq >> 1);
    const bf16x8 v00 = *(const bf16x8*)&Vsb[R0 * 64 + 8 * ((p0 + 0) ^ (R0 & 7))];
    const bf16x8 v01 = *(const bf16x8*)&Vsb[R0 * 64 + 8 * ((p0 + 2) ^ (R0 & 7))];
    const bf16x8 v10 = *(const bf16x8*)&Vsb[R1 * 64 + 8 * ((p0 + 0) ^ (R1 & 7))];
    const bf16x8 v11 = *(const bf16x8*)&Vsb[R1 * 64 + 8 * ((p0 + 2) ^ (R1 & 7))];
    __builtin_amdgcn_s_setprio(1);
    o0 = MFMA32(pa0, v00, o0);
    o1 = MFMA32(pa0, v10, o1);
    o0 = MFMA32(pa1, v01, o0);
    o1 = MFMA32(pa1, v11, o1);
    __builtin_amdgcn_s_setprio(0);
  }
#undef STAGE

  // wave s writes partials over ITS OWN K-dbuf region (8KB = 2048 floats) — disjoint.
  float* me = (float*)&KV[s][0];
#pragma unroll
  for (int rr = 0; rr < 16; ++rr) {
    const int crow = (rr & 3) + 8 * (rr >> 2) + 4 * h5;
    me[crow * 64 + lq] = o0[rr];
    me[crow * 64 + 32 + lq] = o1[rr];
  }
  ll += __shfl_xor(ll, 32);
  if (h5 == 0) mls[s][lq] = ll;
  __syncthreads();

  const float* om0 = (const float*)&KV[0][0];
  const float* om1 = (const float*)&KV[1][0];
  const float* om2 = (const float*)&KV[2][0];
  const float* om3 = (const float*)&KV[3][0];
  const int b = bh >> 4, h = bh & (NHEAD - 1);
  const int r2 = tidx >> 3;       // q-row 0..31
  const int d0 = (tidx & 7) * 8;  // d group (8 elems)
  const float inv =
      __builtin_amdgcn_rcpf(mls[0][r2] + mls[1][r2] + mls[2][r2] + mls[3][r2]);
  const size_t base = (size_t)(b * S_LEN + qbase + r2) * DMODEL + h * HDIM + d0;
#pragma unroll
  for (int i = 0; i < 8; ++i) {
    const int o = r2 * 64 + d0 + i;
    const float v = (om0[o] + om1[o] + om2[o] + om3[o]) * inv;
    ctx[base + i] = f2bf(v);
  }
}

extern "C" void kernel_launch(void* const* d_in, const int* in_sizes, int n_in,
                              void* d_out, int out_size, void* d_ws, size_t ws_size,
                              hipStream_t stream) {
  const float* x = (const float*)d_in[0];
  const float* Wq = (const float*)d_in[1];
  const float* Wk = (const float*)d_in[2];
  const float* Wv = (const float*)d_in[3];
  const float* Wo = (const float*)d_in[4];
  const float* bo = (const float*)d_in[5];

  const size_t XN = (size_t)MROWS * DMODEL;   // 4096*1024
  const size_t WN = (size_t)DMODEL * DMODEL;  // 1024*1024

  short* ws = (short*)d_ws;
  short* xb = ws;
  short* Wqb = xb + XN;  // Wq,Wk,Wv,Wo contiguous ([3072+1024][1024])
  short* Wob = Wqb + 3 * WN;
  short* Qb = Wob + WN;  // Q,K,V contiguous
  short* Kb = Qb + XN;
  short* Vb = Kb + XN;
  short* ctxb = Vb + XN;
  if (ws_size < (5 * XN + 4 * WN) * sizeof(short)) return;

  cvt_kernel<<<2048, 256, 0, stream>>>(x, xb, (int)XN);
  cvt_w4<<<dim3(256, 4), 256, 0, stream>>>(Wq, Wk, Wv, Wo, Wqb);

  gemm_bt<<<dim3(MROWS / 128, 3 * DMODEL / 128), 256, 0, stream>>>(xb, Wqb, Qb);

  attn_kernel<<<2048, 256, 0, stream>>>(Qb, Kb, Vb, ctxb);

  gemm_out<<<dim3(MROWS / 64, DMODEL / 128), 256, 0, stream>>>(ctxb, Wob, (float*)d_out,
                                                               bo);
}